// Round 1
// baseline (844.826 us; speedup 1.0000x reference)
//
#include <hip/hip_runtime.h>

constexpr int N  = 50000;
constexpr int E  = 1600000;
constexpr int ET = E + N;      // with self-loops
constexpr int NF = 128;

__global__ __launch_bounds__(256) void k_zero(int* __restrict__ cnt) {
    int i = blockIdx.x * 256 + threadIdx.x;
    if (i < N) cnt[i] = 0;
}

__global__ __launch_bounds__(256) void k_count(const int* __restrict__ ei, int* __restrict__ cnt) {
    int i = blockIdx.x * 256 + threadIdx.x;
    if (i >= ET) return;
    int d = (i < E) ? ei[E + i] : (i - E);
    atomicAdd(&cnt[d], 1);
}

// single-block exclusive scan over N bins -> off[N+1], cursor copy
__global__ __launch_bounds__(1024) void k_scan(const int* __restrict__ cnt,
                                               int* __restrict__ off, int* __restrict__ cur) {
    __shared__ int buf[1024];
    __shared__ int s_run;
    int t = threadIdx.x;
    if (t == 0) s_run = 0;
    __syncthreads();
    for (int base = 0; base < N; base += 1024) {
        int i = base + t;
        int v = (i < N) ? cnt[i] : 0;
        buf[t] = v;
        __syncthreads();
        for (int o = 1; o < 1024; o <<= 1) {
            int add = (t >= o) ? buf[t - o] : 0;
            __syncthreads();
            buf[t] += add;
            __syncthreads();
        }
        int incl = buf[t];
        int run  = s_run;
        if (i < N) { off[i] = run + incl - v; cur[i] = run + incl - v; }
        __syncthreads();
        if (t == 1023) s_run = run + incl;
        __syncthreads();
    }
    if (t == 0) off[N] = s_run;
}

__global__ __launch_bounds__(256) void k_scatter(const int* __restrict__ ei,
                                                 int* __restrict__ cur, int* __restrict__ srcs) {
    int i = blockIdx.x * 256 + threadIdx.x;
    if (i >= ET) return;
    int s, d;
    if (i < E) { s = ei[i]; d = ei[E + i]; } else { s = i - E; d = i - E; }
    int pos = atomicAdd(&cur[d], 1);
    srcs[pos] = s;
}

// h = X @ W (one block per row), fused alpha_s = h.att_src, alpha_d = h.att_dst
__global__ __launch_bounds__(128) void k_gemm_alpha(
    const float* __restrict__ X, const float* __restrict__ W,
    const float* __restrict__ asv, const float* __restrict__ adv,
    float* __restrict__ H, float* __restrict__ AS, float* __restrict__ AD) {
    int row = blockIdx.x;
    int c = threadIdx.x;
    __shared__ float xs[NF];
    xs[c] = X[row * NF + c];
    __syncthreads();
    float acc = 0.f;
#pragma unroll
    for (int k = 0; k < NF; ++k) acc = fmaf(xs[k], W[k * NF + c], acc);
    H[row * NF + c] = acc;
    float ps = acc * asv[c];
    float pd = acc * adv[c];
#pragma unroll
    for (int o = 32; o > 0; o >>= 1) { ps += __shfl_down(ps, o); pd += __shfl_down(pd, o); }
    __shared__ float r[4];
    if ((c & 63) == 0) { r[(c >> 6) * 2] = ps; r[(c >> 6) * 2 + 1] = pd; }
    __syncthreads();
    if (c == 0) { AS[row] = r[0] + r[2]; AD[row] = r[1] + r[3]; }
}

// per-destination-node softmax + weighted aggregate; block = 128 threads (one column each)
__global__ __launch_bounds__(128) void k_aggregate(
    const float* __restrict__ H, const float* __restrict__ AS, const float* __restrict__ AD,
    const int* __restrict__ off, const int* __restrict__ srcs,
    const float* __restrict__ bias, float* __restrict__ OUT, int act) {
    int d = blockIdx.x;
    int c = threadIdx.x;
    int beg = off[d], end = off[d + 1];
    float ad = AD[d];

    // phase A: segment max
    float lm = -3.0e38f;
    for (int j = beg + c; j < end; j += 128) {
        float s = AS[srcs[j]] + ad;
        float e = (s > 0.f) ? s : 0.2f * s;
        lm = fmaxf(lm, e);
    }
#pragma unroll
    for (int o = 32; o > 0; o >>= 1) lm = fmaxf(lm, __shfl_down(lm, o));
    __shared__ float red[2];
    if ((c & 63) == 0) red[c >> 6] = lm;
    __syncthreads();
    float m = fmaxf(red[0], red[1]);
    __syncthreads();

    // phase B: sum of exp
    float ls = 0.f;
    for (int j = beg + c; j < end; j += 128) {
        float s = AS[srcs[j]] + ad;
        float e = (s > 0.f) ? s : 0.2f * s;
        ls += __expf(e - m);
    }
#pragma unroll
    for (int o = 32; o > 0; o >>= 1) ls += __shfl_down(ls, o);
    if ((c & 63) == 0) red[c >> 6] = ls;
    __syncthreads();
    float inv = 1.0f / (red[0] + red[1] + 1e-16f);

    // phase C: weighted gather-accumulate (thread c owns column c)
    float acc = 0.f;
    for (int j = beg; j < end; ++j) {
        int s = srcs[j];
        float sv = AS[s] + ad;
        float e = (sv > 0.f) ? sv : 0.2f * sv;
        float p = __expf(e - m) * inv;
        acc = fmaf(p, H[s * NF + c], acc);
    }
    acc += bias[c];
    if (act) acc = (acc > 0.f) ? acc : 0.01f * acc;
    OUT[d * NF + c] = acc;
}

extern "C" void kernel_launch(void* const* d_in, const int* in_sizes, int n_in,
                              void* d_out, int out_size, void* d_ws, size_t ws_size,
                              hipStream_t stream) {
    const float* x   = (const float*)d_in[0];
    const int*   ei  = (const int*)d_in[1];
    const float* W1  = (const float*)d_in[2];
    const float* as1 = (const float*)d_in[3];
    const float* ad1 = (const float*)d_in[4];
    const float* b1  = (const float*)d_in[5];
    const float* W2  = (const float*)d_in[6];
    const float* as2 = (const float*)d_in[7];
    const float* ad2 = (const float*)d_in[8];
    const float* b2  = (const float*)d_in[9];
    float* out = (float*)d_out;

    char* p = (char*)d_ws;
    auto alloc = [&](size_t bytes) { char* r = p; p += (bytes + 255) & ~size_t(255); return (void*)r; };
    int* cnt    = (int*)alloc(sizeof(int) * N);
    int* off    = (int*)alloc(sizeof(int) * (N + 1));
    int* cur    = (int*)alloc(sizeof(int) * N);
    int* srcs   = (int*)alloc(sizeof(int) * ET);
    float* H    = (float*)alloc(sizeof(float) * (size_t)N * NF);
    float* AS   = (float*)alloc(sizeof(float) * N);
    float* AD   = (float*)alloc(sizeof(float) * N);
    float* HMID = (float*)alloc(sizeof(float) * (size_t)N * NF);

    k_zero<<<(N + 255) / 256, 256, 0, stream>>>(cnt);
    k_count<<<(ET + 255) / 256, 256, 0, stream>>>(ei, cnt);
    k_scan<<<1, 1024, 0, stream>>>(cnt, off, cur);
    k_scatter<<<(ET + 255) / 256, 256, 0, stream>>>(ei, cur, srcs);

    // layer 1
    k_gemm_alpha<<<N, 128, 0, stream>>>(x, W1, as1, ad1, H, AS, AD);
    k_aggregate<<<N, 128, 0, stream>>>(H, AS, AD, off, srcs, b1, HMID, 1);
    // layer 2
    k_gemm_alpha<<<N, 128, 0, stream>>>(HMID, W2, as2, ad2, H, AS, AD);
    k_aggregate<<<N, 128, 0, stream>>>(H, AS, AD, off, srcs, b2, out, 0);
}

// Round 2
// 536.310 us; speedup vs baseline: 1.5753x; 1.5753x over previous
//
#include <hip/hip_runtime.h>

constexpr int N  = 50000;
constexpr int E  = 1600000;
constexpr int ET = E + N;      // with self-loops
constexpr int NF = 128;
constexpr int GR = 16;         // gemm rows per block
constexpr int NCHUNK = (N + 1023) / 1024;   // 49

__global__ __launch_bounds__(256) void k_zero(int* __restrict__ cnt) {
    int i = blockIdx.x * 256 + threadIdx.x;
    if (i < N) cnt[i] = 0;
}

__global__ __launch_bounds__(256) void k_count(const int* __restrict__ ei, int* __restrict__ cnt) {
    int i = blockIdx.x * 256 + threadIdx.x;
    if (i >= ET) return;
    int d = (i < E) ? ei[E + i] : (i - E);
    atomicAdd(&cnt[d], 1);
}

// multi-block scan: 1) per-chunk local exclusive scan + chunk totals
__global__ __launch_bounds__(1024) void k_scan1(const int* __restrict__ cnt,
                                                int* __restrict__ off, int* __restrict__ part) {
    __shared__ int buf[1024];
    int t = threadIdx.x;
    int i = blockIdx.x * 1024 + t;
    int v = (i < N) ? cnt[i] : 0;
    buf[t] = v;
    __syncthreads();
    for (int o = 1; o < 1024; o <<= 1) {
        int a = (t >= o) ? buf[t - o] : 0;
        __syncthreads();
        buf[t] += a;
        __syncthreads();
    }
    if (i < N) off[i] = buf[t] - v;           // local exclusive
    if (t == 1023) part[blockIdx.x] = buf[1023];
}

// 2) scan of 49 chunk totals (single small block)
__global__ __launch_bounds__(64) void k_scan2(int* __restrict__ part) {
    __shared__ int buf[64];
    int t = threadIdx.x;
    int v = (t < NCHUNK) ? part[t] : 0;
    buf[t] = v;
    __syncthreads();
    for (int o = 1; o < 64; o <<= 1) {
        int a = (t >= o) ? buf[t - o] : 0;
        __syncthreads();
        buf[t] += a;
        __syncthreads();
    }
    if (t < NCHUNK) part[t] = buf[t] - v;     // exclusive chunk offset
}

// 3) add chunk offsets, produce cursor copy, set off[N]
__global__ __launch_bounds__(1024) void k_scan3(int* __restrict__ off, const int* __restrict__ part,
                                                int* __restrict__ cur) {
    int i = blockIdx.x * 1024 + threadIdx.x;
    if (i < N) {
        int v = off[i] + part[blockIdx.x];
        off[i] = v;
        cur[i] = v;
    }
    if (i == 0) off[N] = ET;
}

__global__ __launch_bounds__(256) void k_scatter(const int* __restrict__ ei,
                                                 int* __restrict__ cur, int* __restrict__ srcs) {
    int i = blockIdx.x * 256 + threadIdx.x;
    if (i >= ET) return;
    int s, d;
    if (i < E) { s = ei[i]; d = ei[E + i]; } else { s = i - E; d = i - E; }
    int pos = atomicAdd(&cur[d], 1);
    srcs[pos] = s;
}

// H = X @ W, 16 rows per block, x-tile staged in LDS as float4, W streamed from L2
__global__ __launch_bounds__(256) void k_gemm(
    const float* __restrict__ X, const float* __restrict__ W, float* __restrict__ H) {
    int brow = blockIdx.x * GR;
    int t = threadIdx.x;
    int c = t & 127, ty = t >> 7;             // ty in {0,1}: rows ty*8 .. ty*8+7
    __shared__ float4 xs[GR][NF / 4];         // 16 x 128 floats = 8KB
    for (int idx = t; idx < GR * (NF / 4); idx += 256) {
        int r = idx >> 5, q = idx & 31;
        xs[r][q] = ((const float4*)X)[(size_t)(brow + r) * (NF / 4) + q];
    }
    __syncthreads();
    float acc[8] = {0.f, 0.f, 0.f, 0.f, 0.f, 0.f, 0.f, 0.f};
#pragma unroll 4
    for (int k4 = 0; k4 < NF / 4; ++k4) {
        float w0 = W[(k4 * 4 + 0) * NF + c];
        float w1 = W[(k4 * 4 + 1) * NF + c];
        float w2 = W[(k4 * 4 + 2) * NF + c];
        float w3 = W[(k4 * 4 + 3) * NF + c];
#pragma unroll
        for (int rr = 0; rr < 8; ++rr) {
            float4 x4 = xs[ty * 8 + rr][k4];
            acc[rr] = fmaf(x4.x, w0, fmaf(x4.y, w1, fmaf(x4.z, w2, fmaf(x4.w, w3, acc[rr]))));
        }
    }
#pragma unroll
    for (int rr = 0; rr < 8; ++rr)
        H[(size_t)(brow + ty * 8 + rr) * NF + c] = acc[rr];
}

// AS = H . att_src, AD = H . att_dst  (one wave per row)
__global__ __launch_bounds__(256) void k_alpha(
    const float* __restrict__ H, const float* __restrict__ asv, const float* __restrict__ adv,
    float* __restrict__ AS, float* __restrict__ AD) {
    int row = blockIdx.x * 4 + (threadIdx.x >> 6);
    int lane = threadIdx.x & 63;
    float2 h2 = ((const float2*)H)[(size_t)row * 64 + lane];
    float2 a2 = ((const float2*)asv)[lane];
    float2 d2 = ((const float2*)adv)[lane];
    float ps = h2.x * a2.x + h2.y * a2.y;
    float pd = h2.x * d2.x + h2.y * d2.y;
#pragma unroll
    for (int o = 32; o > 0; o >>= 1) { ps += __shfl_down(ps, o); pd += __shfl_down(pd, o); }
    if (lane == 0) { AS[row] = ps; AD[row] = pd; }
}

// per-destination softmax + aggregate: 4 edges in flight x float4 columns
__global__ __launch_bounds__(128) void k_aggregate(
    const float* __restrict__ H, const float* __restrict__ AS, const float* __restrict__ AD,
    const int* __restrict__ off, const int* __restrict__ srcs,
    const float* __restrict__ bias, float* __restrict__ OUT, int act) {
    int d = blockIdx.x;
    int t = threadIdx.x;
    int tx = t & 31, u = t >> 5;              // u: edge slot 0..3
    int beg = off[d], end = off[d + 1];
    float ad = AD[d];

    // phase A: segment max (strided over 128 threads)
    float lm = -3.0e38f;
    for (int j = beg + t; j < end; j += 128) {
        float s = AS[srcs[j]] + ad;
        lm = fmaxf(lm, (s > 0.f) ? s : 0.2f * s);
    }
#pragma unroll
    for (int o = 32; o > 0; o >>= 1) lm = fmaxf(lm, __shfl_xor(lm, o));
    __shared__ float red[2];
    if ((t & 63) == 0) red[t >> 6] = lm;
    __syncthreads();
    float m = fmaxf(red[0], red[1]);

    // phase B+C merged: unnormalized accumulate, 4 edges in flight
    float4 acc = {0.f, 0.f, 0.f, 0.f};
    float ls = 0.f;
    for (int j0 = beg; j0 < end; j0 += 4) {
        int j = j0 + u;
        if (j < end) {
            int s = srcs[j];
            float sv = AS[s] + ad;
            sv = (sv > 0.f) ? sv : 0.2f * sv;
            float e = __expf(sv - m);
            ls += e;
            float4 h4 = ((const float4*)H)[(size_t)s * 32 + tx];
            acc.x = fmaf(e, h4.x, acc.x);
            acc.y = fmaf(e, h4.y, acc.y);
            acc.z = fmaf(e, h4.z, acc.z);
            acc.w = fmaf(e, h4.w, acc.w);
        }
    }
    // combine edge slots: in-wave u-pairs via xor 32, then cross-wave via LDS
    ls += __shfl_xor(ls, 32);
    acc.x += __shfl_xor(acc.x, 32);
    acc.y += __shfl_xor(acc.y, 32);
    acc.z += __shfl_xor(acc.z, 32);
    acc.w += __shfl_xor(acc.w, 32);
    __shared__ float4 sacc[32];
    __shared__ float sls;
    if (t >= 64 && t < 96) sacc[tx] = acc;
    if (t == 64) sls = ls;
    __syncthreads();
    if (t < 32) {
        float4 a2 = sacc[tx];
        float inv = 1.f / (ls + sls + 1e-16f);
        float4 b4 = ((const float4*)bias)[tx];
        float4 o;
        o.x = (acc.x + a2.x) * inv + b4.x;
        o.y = (acc.y + a2.y) * inv + b4.y;
        o.z = (acc.z + a2.z) * inv + b4.z;
        o.w = (acc.w + a2.w) * inv + b4.w;
        if (act) {
            o.x = (o.x > 0.f) ? o.x : 0.01f * o.x;
            o.y = (o.y > 0.f) ? o.y : 0.01f * o.y;
            o.z = (o.z > 0.f) ? o.z : 0.01f * o.z;
            o.w = (o.w > 0.f) ? o.w : 0.01f * o.w;
        }
        ((float4*)OUT)[(size_t)d * 32 + tx] = o;
    }
}

extern "C" void kernel_launch(void* const* d_in, const int* in_sizes, int n_in,
                              void* d_out, int out_size, void* d_ws, size_t ws_size,
                              hipStream_t stream) {
    const float* x   = (const float*)d_in[0];
    const int*   ei  = (const int*)d_in[1];
    const float* W1  = (const float*)d_in[2];
    const float* as1 = (const float*)d_in[3];
    const float* ad1 = (const float*)d_in[4];
    const float* b1  = (const float*)d_in[5];
    const float* W2  = (const float*)d_in[6];
    const float* as2 = (const float*)d_in[7];
    const float* ad2 = (const float*)d_in[8];
    const float* b2  = (const float*)d_in[9];
    float* out = (float*)d_out;

    char* p = (char*)d_ws;
    auto alloc = [&](size_t bytes) { char* r = p; p += (bytes + 255) & ~size_t(255); return (void*)r; };
    int* cnt    = (int*)alloc(sizeof(int) * N);
    int* off    = (int*)alloc(sizeof(int) * (N + 1));
    int* cur    = (int*)alloc(sizeof(int) * N);
    int* part   = (int*)alloc(sizeof(int) * NCHUNK);
    int* srcs   = (int*)alloc(sizeof(int) * ET);
    float* H    = (float*)alloc(sizeof(float) * (size_t)N * NF);
    float* AS   = (float*)alloc(sizeof(float) * N);
    float* AD   = (float*)alloc(sizeof(float) * N);
    float* HMID = (float*)alloc(sizeof(float) * (size_t)N * NF);

    k_zero<<<(N + 255) / 256, 256, 0, stream>>>(cnt);
    k_count<<<(ET + 255) / 256, 256, 0, stream>>>(ei, cnt);
    k_scan1<<<NCHUNK, 1024, 0, stream>>>(cnt, off, part);
    k_scan2<<<1, 64, 0, stream>>>(part);
    k_scan3<<<NCHUNK, 1024, 0, stream>>>(off, part, cur);
    k_scatter<<<(ET + 255) / 256, 256, 0, stream>>>(ei, cur, srcs);

    // layer 1
    k_gemm<<<N / GR, 256, 0, stream>>>(x, W1, H);
    k_alpha<<<N / 4, 256, 0, stream>>>(H, as1, ad1, AS, AD);
    k_aggregate<<<N, 128, 0, stream>>>(H, AS, AD, off, srcs, b1, HMID, 1);
    // layer 2
    k_gemm<<<N / GR, 256, 0, stream>>>(HMID, W2, H);
    k_alpha<<<N / 4, 256, 0, stream>>>(H, as2, ad2, AS, AD);
    k_aggregate<<<N, 128, 0, stream>>>(H, AS, AD, off, srcs, b2, out, 0);
}

// Round 3
// 389.883 us; speedup vs baseline: 2.1669x; 1.3756x over previous
//
#include <hip/hip_runtime.h>

constexpr int N  = 50000;
constexpr int E  = 1600000;
constexpr int ET = E + N;                   // with self-loops
constexpr int NF = 128;
constexpr int NB = (N + 127) / 128;         // 391 dst-buckets of 128 nodes
constexpr int EPB  = 8192;                  // edges per block (hist/scatter)
constexpr int NBLK = (ET + EPB - 1) / EPB;  // 202
constexpr int DCAP = 8192;                  // LDS edge capacity in k_csr
constexpr int GR = 16;                      // gemm rows per block

__global__ __launch_bounds__(512) void k_zero_b(int* __restrict__ bcnt) {
    int i = threadIdx.x;
    if (i < NB) bcnt[i] = 0;
}

// per-block LDS histogram over 391 dst-buckets
__global__ __launch_bounds__(1024) void k_hist(const int* __restrict__ ei, int* __restrict__ bcnt) {
    __shared__ int h[NB];
    int t = threadIdx.x;
    for (int i = t; i < NB; i += 1024) h[i] = 0;
    __syncthreads();
    int base = blockIdx.x * EPB;
#pragma unroll
    for (int k = 0; k < EPB / 1024; ++k) {
        int i = base + k * 1024 + t;
        if (i < ET) {
            int d = (i < E) ? ei[E + i] : (i - E);
            atomicAdd(&h[d >> 7], 1);
        }
    }
    __syncthreads();
    for (int i = t; i < NB; i += 1024)
        if (h[i]) atomicAdd(&bcnt[i], h[i]);
}

// scan 391 bucket counts -> bbase (exclusive), bcur copy; set sentinels
__global__ __launch_bounds__(512) void k_bscan(const int* __restrict__ bcnt,
                                               int* __restrict__ bbase, int* __restrict__ bcur,
                                               int* __restrict__ off) {
    __shared__ int buf[512];
    int t = threadIdx.x;
    int v = (t < NB) ? bcnt[t] : 0;
    buf[t] = v;
    __syncthreads();
    for (int o = 1; o < 512; o <<= 1) {
        int a = (t >= o) ? buf[t - o] : 0;
        __syncthreads();
        buf[t] += a;
        __syncthreads();
    }
    if (t < NB) { bbase[t] = buf[t] - v; bcur[t] = buf[t] - v; }
    if (t == 0) { bbase[NB] = ET; off[N] = ET; }
}

// bucket-binned scatter: stash 8 edges in registers, LDS-count, reserve one
// contiguous global run per (block,bucket), append packed records
__global__ __launch_bounds__(1024) void k_binscatter(const int* __restrict__ ei,
                                                     int* __restrict__ bcur,
                                                     int* __restrict__ packed) {
    __shared__ int h[NB], lcur[NB], garr[NB];
    int t = threadIdx.x;
    for (int i = t; i < NB; i += 1024) h[i] = 0;
    __syncthreads();
    int base = blockIdx.x * EPB;
    int pk[EPB / 1024];
    int bk[EPB / 1024];
#pragma unroll
    for (int k = 0; k < EPB / 1024; ++k) {
        int i = base + k * 1024 + t;
        if (i < ET) {
            int s, d;
            if (i < E) { s = ei[i]; d = ei[E + i]; } else { s = i - E; d = i - E; }
            bk[k] = d >> 7;
            pk[k] = s | ((d & 127) << 16);
            atomicAdd(&h[bk[k]], 1);
        } else bk[k] = -1;
    }
    __syncthreads();
    for (int i = t; i < NB; i += 1024) {
        lcur[i] = 0;
        garr[i] = h[i] ? atomicAdd(&bcur[i], h[i]) : 0;
    }
    __syncthreads();
#pragma unroll
    for (int k = 0; k < EPB / 1024; ++k) {
        if (bk[k] >= 0) {
            int p = garr[bk[k]] + atomicAdd(&lcur[bk[k]], 1);
            packed[p] = pk[k];
        }
    }
}

// one block per bucket: local CSR over its 128 dsts in LDS, coalesced off/srcs writes
__global__ __launch_bounds__(1024) void k_csr(const int* __restrict__ packed,
                                              const int* __restrict__ bbase,
                                              int* __restrict__ off, int* __restrict__ srcs) {
    int b = blockIdx.x;
    int t = threadIdx.x;
    int s0 = bbase[b], s1 = bbase[b + 1];
    int n = s1 - s0;
    __shared__ int buf[DCAP];
    __shared__ int h[128], sc[128], lcur[128];
    for (int i = t; i < n && i < DCAP; i += 1024) buf[i] = packed[s0 + i];
    if (t < 128) { h[t] = 0; lcur[t] = 0; }
    __syncthreads();
    for (int i = t; i < n; i += 1024) {
        int p = (i < DCAP) ? buf[i] : packed[s0 + i];
        atomicAdd(&h[(p >> 16) & 127], 1);
    }
    __syncthreads();
    if (t < 128) sc[t] = h[t];
    __syncthreads();
    for (int o = 1; o < 128; o <<= 1) {
        int a = (t >= o && t < 128) ? sc[t - o] : 0;
        __syncthreads();
        if (t < 128) sc[t] += a;
        __syncthreads();
    }
    // sc now inclusive; exclusive = sc - h
    if (t < 128) {
        int d = b * 128 + t;
        if (d < N) off[d] = s0 + sc[t] - h[t];
    }
    __syncthreads();
    for (int i = t; i < n; i += 1024) {
        int p = (i < DCAP) ? buf[i] : packed[s0 + i];
        int dl = (p >> 16) & 127;
        int pos = s0 + (sc[dl] - h[dl]) + atomicAdd(&lcur[dl], 1);
        srcs[pos] = p & 0xFFFF;
    }
}

// H = X @ W, 16 rows per block, x-tile staged in LDS as float4, W streamed from L2
__global__ __launch_bounds__(256) void k_gemm(
    const float* __restrict__ X, const float* __restrict__ W, float* __restrict__ H) {
    int brow = blockIdx.x * GR;
    int t = threadIdx.x;
    int c = t & 127, ty = t >> 7;
    __shared__ float4 xs[GR][NF / 4];
    for (int idx = t; idx < GR * (NF / 4); idx += 256) {
        int r = idx >> 5, q = idx & 31;
        xs[r][q] = ((const float4*)X)[(size_t)(brow + r) * (NF / 4) + q];
    }
    __syncthreads();
    float acc[8] = {0.f, 0.f, 0.f, 0.f, 0.f, 0.f, 0.f, 0.f};
#pragma unroll 4
    for (int k4 = 0; k4 < NF / 4; ++k4) {
        float w0 = W[(k4 * 4 + 0) * NF + c];
        float w1 = W[(k4 * 4 + 1) * NF + c];
        float w2 = W[(k4 * 4 + 2) * NF + c];
        float w3 = W[(k4 * 4 + 3) * NF + c];
#pragma unroll
        for (int rr = 0; rr < 8; ++rr) {
            float4 x4 = xs[ty * 8 + rr][k4];
            acc[rr] = fmaf(x4.x, w0, fmaf(x4.y, w1, fmaf(x4.z, w2, fmaf(x4.w, w3, acc[rr]))));
        }
    }
#pragma unroll
    for (int rr = 0; rr < 8; ++rr)
        H[(size_t)(brow + ty * 8 + rr) * NF + c] = acc[rr];
}

// AS = H . att_src, AD = H . att_dst  (one wave per row)
__global__ __launch_bounds__(256) void k_alpha(
    const float* __restrict__ H, const float* __restrict__ asv, const float* __restrict__ adv,
    float* __restrict__ AS, float* __restrict__ AD) {
    int row = blockIdx.x * 4 + (threadIdx.x >> 6);
    int lane = threadIdx.x & 63;
    float2 h2 = ((const float2*)H)[(size_t)row * 64 + lane];
    float2 a2 = ((const float2*)asv)[lane];
    float2 d2 = ((const float2*)adv)[lane];
    float ps = h2.x * a2.x + h2.y * a2.y;
    float pd = h2.x * d2.x + h2.y * d2.y;
#pragma unroll
    for (int o = 32; o > 0; o >>= 1) { ps += __shfl_down(ps, o); pd += __shfl_down(pd, o); }
    if (lane == 0) { AS[row] = ps; AD[row] = pd; }
}

// per-destination softmax + aggregate: 4 edges in flight x float4 columns
__global__ __launch_bounds__(128) void k_aggregate(
    const float* __restrict__ H, const float* __restrict__ AS, const float* __restrict__ AD,
    const int* __restrict__ off, const int* __restrict__ srcs,
    const float* __restrict__ bias, float* __restrict__ OUT, int act) {
    int d = blockIdx.x;
    int t = threadIdx.x;
    int tx = t & 31, u = t >> 5;
    int beg = off[d], end = off[d + 1];
    float ad = AD[d];

    float lm = -3.0e38f;
    for (int j = beg + t; j < end; j += 128) {
        float s = AS[srcs[j]] + ad;
        lm = fmaxf(lm, (s > 0.f) ? s : 0.2f * s);
    }
#pragma unroll
    for (int o = 32; o > 0; o >>= 1) lm = fmaxf(lm, __shfl_xor(lm, o));
    __shared__ float red[2];
    if ((t & 63) == 0) red[t >> 6] = lm;
    __syncthreads();
    float m = fmaxf(red[0], red[1]);

    float4 acc = {0.f, 0.f, 0.f, 0.f};
    float ls = 0.f;
    for (int j0 = beg; j0 < end; j0 += 4) {
        int j = j0 + u;
        if (j < end) {
            int s = srcs[j];
            float sv = AS[s] + ad;
            sv = (sv > 0.f) ? sv : 0.2f * sv;
            float e = __expf(sv - m);
            ls += e;
            float4 h4 = ((const float4*)H)[(size_t)s * 32 + tx];
            acc.x = fmaf(e, h4.x, acc.x);
            acc.y = fmaf(e, h4.y, acc.y);
            acc.z = fmaf(e, h4.z, acc.z);
            acc.w = fmaf(e, h4.w, acc.w);
        }
    }
    ls += __shfl_xor(ls, 32);
    acc.x += __shfl_xor(acc.x, 32);
    acc.y += __shfl_xor(acc.y, 32);
    acc.z += __shfl_xor(acc.z, 32);
    acc.w += __shfl_xor(acc.w, 32);
    __shared__ float4 sacc[32];
    __shared__ float sls;
    if (t >= 64 && t < 96) sacc[tx] = acc;
    if (t == 64) sls = ls;
    __syncthreads();
    if (t < 32) {
        float4 a2 = sacc[tx];
        float inv = 1.f / (ls + sls + 1e-16f);
        float4 b4 = ((const float4*)bias)[tx];
        float4 o;
        o.x = (acc.x + a2.x) * inv + b4.x;
        o.y = (acc.y + a2.y) * inv + b4.y;
        o.z = (acc.z + a2.z) * inv + b4.z;
        o.w = (acc.w + a2.w) * inv + b4.w;
        if (act) {
            o.x = (o.x > 0.f) ? o.x : 0.01f * o.x;
            o.y = (o.y > 0.f) ? o.y : 0.01f * o.y;
            o.z = (o.z > 0.f) ? o.z : 0.01f * o.z;
            o.w = (o.w > 0.f) ? o.w : 0.01f * o.w;
        }
        ((float4*)OUT)[(size_t)d * 32 + tx] = o;
    }
}

extern "C" void kernel_launch(void* const* d_in, const int* in_sizes, int n_in,
                              void* d_out, int out_size, void* d_ws, size_t ws_size,
                              hipStream_t stream) {
    const float* x   = (const float*)d_in[0];
    const int*   ei  = (const int*)d_in[1];
    const float* W1  = (const float*)d_in[2];
    const float* as1 = (const float*)d_in[3];
    const float* ad1 = (const float*)d_in[4];
    const float* b1  = (const float*)d_in[5];
    const float* W2  = (const float*)d_in[6];
    const float* as2 = (const float*)d_in[7];
    const float* ad2 = (const float*)d_in[8];
    const float* b2  = (const float*)d_in[9];
    float* out = (float*)d_out;

    char* p = (char*)d_ws;
    auto alloc = [&](size_t bytes) { char* r = p; p += (bytes + 255) & ~size_t(255); return (void*)r; };
    int* bcnt  = (int*)alloc(sizeof(int) * NB);
    int* bbase = (int*)alloc(sizeof(int) * (NB + 1));
    int* bcur  = (int*)alloc(sizeof(int) * NB);
    int* off   = (int*)alloc(sizeof(int) * (N + 1));
    int* srcs  = (int*)alloc(sizeof(int) * ET);
    float* H   = (float*)alloc(sizeof(float) * (size_t)N * NF);
    float* AS  = (float*)alloc(sizeof(float) * N);
    float* AD  = (float*)alloc(sizeof(float) * N);
    float* HMID = (float*)alloc(sizeof(float) * (size_t)N * NF);
    int* packed = (int*)HMID;   // alias: packed is dead before HMID is first written

    // CSR build (bucketed two-level counting sort)
    k_zero_b<<<1, 512, 0, stream>>>(bcnt);
    k_hist<<<NBLK, 1024, 0, stream>>>(ei, bcnt);
    k_bscan<<<1, 512, 0, stream>>>(bcnt, bbase, bcur, off);
    k_binscatter<<<NBLK, 1024, 0, stream>>>(ei, bcur, packed);
    k_csr<<<NB, 1024, 0, stream>>>(packed, bbase, off, srcs);

    // layer 1
    k_gemm<<<N / GR, 256, 0, stream>>>(x, W1, H);
    k_alpha<<<N / 4, 256, 0, stream>>>(H, as1, ad1, AS, AD);
    k_aggregate<<<N, 128, 0, stream>>>(H, AS, AD, off, srcs, b1, HMID, 1);
    // layer 2
    k_gemm<<<N / GR, 256, 0, stream>>>(HMID, W2, H);
    k_alpha<<<N / 4, 256, 0, stream>>>(H, as2, ad2, AS, AD);
    k_aggregate<<<N, 128, 0, stream>>>(H, AS, AD, off, srcs, b2, out, 0);
}

// Round 4
// 302.671 us; speedup vs baseline: 2.7912x; 1.2881x over previous
//
#include <hip/hip_runtime.h>
#include <hip/hip_fp16.h>

constexpr int N  = 50000;
constexpr int E  = 1600000;
constexpr int ET = E + N;                   // with self-loops
constexpr int NF = 128;
constexpr int NB = (N + 127) / 128;         // 391 dst-buckets of 128 nodes
constexpr int EPB  = 8192;                  // edges per block (hist/scatter)
constexpr int NBLK = (ET + EPB - 1) / EPB;  // 202
constexpr int DCAP = 8192;                  // LDS edge capacity in k_csr
constexpr int GR = 16;                      // gemm rows per block

__global__ __launch_bounds__(512) void k_zero_b(int* __restrict__ bcnt) {
    int i = threadIdx.x;
    if (i < NB) bcnt[i] = 0;
}

// per-block LDS histogram over 391 dst-buckets
__global__ __launch_bounds__(1024) void k_hist(const int* __restrict__ ei, int* __restrict__ bcnt) {
    __shared__ int h[NB];
    int t = threadIdx.x;
    for (int i = t; i < NB; i += 1024) h[i] = 0;
    __syncthreads();
    int base = blockIdx.x * EPB;
#pragma unroll
    for (int k = 0; k < EPB / 1024; ++k) {
        int i = base + k * 1024 + t;
        if (i < ET) {
            int d = (i < E) ? ei[E + i] : (i - E);
            atomicAdd(&h[d >> 7], 1);
        }
    }
    __syncthreads();
    for (int i = t; i < NB; i += 1024)
        if (h[i]) atomicAdd(&bcnt[i], h[i]);
}

// scan 391 bucket counts -> bbase (exclusive), bcur copy; set sentinels
__global__ __launch_bounds__(512) void k_bscan(const int* __restrict__ bcnt,
                                               int* __restrict__ bbase, int* __restrict__ bcur,
                                               int* __restrict__ off) {
    __shared__ int buf[512];
    int t = threadIdx.x;
    int v = (t < NB) ? bcnt[t] : 0;
    buf[t] = v;
    __syncthreads();
    for (int o = 1; o < 512; o <<= 1) {
        int a = (t >= o) ? buf[t - o] : 0;
        __syncthreads();
        buf[t] += a;
        __syncthreads();
    }
    if (t < NB) { bbase[t] = buf[t] - v; bcur[t] = buf[t] - v; }
    if (t == 0) { bbase[NB] = ET; off[N] = ET; }
}

// bucket-binned scatter: stash 8 edges in registers, LDS-count, reserve one
// contiguous global run per (block,bucket), append packed (src | dlow<<16)
__global__ __launch_bounds__(1024) void k_binscatter(const int* __restrict__ ei,
                                                     int* __restrict__ bcur,
                                                     int* __restrict__ packed) {
    __shared__ int h[NB], lcur[NB], garr[NB];
    int t = threadIdx.x;
    for (int i = t; i < NB; i += 1024) h[i] = 0;
    __syncthreads();
    int base = blockIdx.x * EPB;
    int pk[EPB / 1024];
    int bk[EPB / 1024];
#pragma unroll
    for (int k = 0; k < EPB / 1024; ++k) {
        int i = base + k * 1024 + t;
        if (i < ET) {
            int s, d;
            if (i < E) { s = ei[i]; d = ei[E + i]; } else { s = i - E; d = i - E; }
            bk[k] = d >> 7;
            pk[k] = s | ((d & 127) << 16);
            atomicAdd(&h[bk[k]], 1);
        } else bk[k] = -1;
    }
    __syncthreads();
    for (int i = t; i < NB; i += 1024) {
        lcur[i] = 0;
        garr[i] = h[i] ? atomicAdd(&bcur[i], h[i]) : 0;
    }
    __syncthreads();
#pragma unroll
    for (int k = 0; k < EPB / 1024; ++k) {
        if (bk[k] >= 0) {
            int p = garr[bk[k]] + atomicAdd(&lcur[bk[k]], 1);
            packed[p] = pk[k];
        }
    }
}

// one block per bucket: local CSR over its 128 dsts in LDS, coalesced off/srcs writes
__global__ __launch_bounds__(1024) void k_csr(const int* __restrict__ packed,
                                              const int* __restrict__ bbase,
                                              int* __restrict__ off, int* __restrict__ srcs) {
    int b = blockIdx.x;
    int t = threadIdx.x;
    int s0 = bbase[b], s1 = bbase[b + 1];
    int n = s1 - s0;
    __shared__ int buf[DCAP];
    __shared__ int h[128], sc[128], lcur[128];
    for (int i = t; i < n && i < DCAP; i += 1024) buf[i] = packed[s0 + i];
    if (t < 128) { h[t] = 0; lcur[t] = 0; }
    __syncthreads();
    for (int i = t; i < n; i += 1024) {
        int p = (i < DCAP) ? buf[i] : packed[s0 + i];
        atomicAdd(&h[(p >> 16) & 127], 1);
    }
    __syncthreads();
    if (t < 128) sc[t] = h[t];
    __syncthreads();
    for (int o = 1; o < 128; o <<= 1) {
        int a = (t >= o && t < 128) ? sc[t - o] : 0;
        __syncthreads();
        if (t < 128) sc[t] += a;
        __syncthreads();
    }
    if (t < 128) {
        int d = b * 128 + t;
        if (d < N) off[d] = s0 + sc[t] - h[t];
    }
    __syncthreads();
    for (int i = t; i < n; i += 1024) {
        int p = (i < DCAP) ? buf[i] : packed[s0 + i];
        int dl = (p >> 16) & 127;
        int pos = s0 + (sc[dl] - h[dl]) + atomicAdd(&lcur[dl], 1);
        srcs[pos] = p & 0xFFFF;
    }
}

// H16 = fp16(X @ W), alpha projections fused from fp32 accumulators
__global__ __launch_bounds__(256) void k_gemm(
    const float* __restrict__ X, const float* __restrict__ W,
    const float* __restrict__ asv, const float* __restrict__ adv,
    __half* __restrict__ H16, float* __restrict__ AS, float* __restrict__ AD) {
    int brow = blockIdx.x * GR;
    int t = threadIdx.x;
    int c = t & 127, ty = t >> 7;
    __shared__ float4 xs[GR][NF / 4];
    for (int idx = t; idx < GR * (NF / 4); idx += 256) {
        int r = idx >> 5, q = idx & 31;
        xs[r][q] = ((const float4*)X)[(size_t)(brow + r) * (NF / 4) + q];
    }
    __syncthreads();
    float acc[8] = {0.f, 0.f, 0.f, 0.f, 0.f, 0.f, 0.f, 0.f};
#pragma unroll 4
    for (int k4 = 0; k4 < NF / 4; ++k4) {
        float w0 = W[(k4 * 4 + 0) * NF + c];
        float w1 = W[(k4 * 4 + 1) * NF + c];
        float w2 = W[(k4 * 4 + 2) * NF + c];
        float w3 = W[(k4 * 4 + 3) * NF + c];
#pragma unroll
        for (int rr = 0; rr < 8; ++rr) {
            float4 x4 = xs[ty * 8 + rr][k4];
            acc[rr] = fmaf(x4.x, w0, fmaf(x4.y, w1, fmaf(x4.z, w2, fmaf(x4.w, w3, acc[rr]))));
        }
    }
    float avs = asv[c], avd = adv[c];
    __shared__ float rsum[GR][2][2];   // [row][as/ad][wave-half]
#pragma unroll
    for (int rr = 0; rr < 8; ++rr) {
        H16[(size_t)(brow + ty * 8 + rr) * NF + c] = __float2half_rn(acc[rr]);
        float ps = acc[rr] * avs;
        float pd = acc[rr] * avd;
#pragma unroll
        for (int o = 32; o > 0; o >>= 1) { ps += __shfl_down(ps, o); pd += __shfl_down(pd, o); }
        if ((t & 63) == 0) {
            int half = (t >> 6) & 1;
            rsum[ty * 8 + rr][0][half] = ps;
            rsum[ty * 8 + rr][1][half] = pd;
        }
    }
    __syncthreads();
    if (t < GR) {
        AS[brow + t] = rsum[t][0][0] + rsum[t][0][1];
        AD[brow + t] = rsum[t][1][0] + rsum[t][1][1];
    }
}

// per-destination softmax + aggregate: 8 edge slots x 16 lanes (8 cols each, fp16 gather)
__global__ __launch_bounds__(128) void k_aggregate(
    const __half* __restrict__ H16, const float* __restrict__ AS, const float* __restrict__ AD,
    const int* __restrict__ off, const int* __restrict__ srcs,
    const float* __restrict__ bias, float* __restrict__ OUT, int act) {
    int d = blockIdx.x;
    int t = threadIdx.x;
    int tx = t & 15, u = t >> 4;              // u: edge slot 0..7
    int beg = off[d], end = off[d + 1];
    float ad = AD[d];

    // phase A: segment max (strided over 128 threads)
    float lm = -3.0e38f;
    for (int j = beg + t; j < end; j += 128) {
        float s = AS[srcs[j]] + ad;
        lm = fmaxf(lm, (s > 0.f) ? s : 0.2f * s);
    }
#pragma unroll
    for (int o = 32; o > 0; o >>= 1) lm = fmaxf(lm, __shfl_xor(lm, o));
    __shared__ float red[2];
    if ((t & 63) == 0) red[t >> 6] = lm;
    __syncthreads();
    float m = fmaxf(red[0], red[1]);

    // merged softmax + unnormalized accumulate, 8 edges in flight
    float acc[8] = {0.f, 0.f, 0.f, 0.f, 0.f, 0.f, 0.f, 0.f};
    float ls = 0.f;
    for (int j0 = beg; j0 < end; j0 += 8) {
        int j = j0 + u;
        if (j < end) {
            int s = srcs[j];
            float sv = AS[s] + ad;
            sv = (sv > 0.f) ? sv : 0.2f * sv;
            float e = __expf(sv - m);
            ls += e;
            union { float4 f; __half2 h[4]; } v;
            v.f = *reinterpret_cast<const float4*>(H16 + (size_t)s * NF + tx * 8);
            float2 f0 = __half22float2(v.h[0]);
            float2 f1 = __half22float2(v.h[1]);
            float2 f2 = __half22float2(v.h[2]);
            float2 f3 = __half22float2(v.h[3]);
            acc[0] = fmaf(e, f0.x, acc[0]); acc[1] = fmaf(e, f0.y, acc[1]);
            acc[2] = fmaf(e, f1.x, acc[2]); acc[3] = fmaf(e, f1.y, acc[3]);
            acc[4] = fmaf(e, f2.x, acc[4]); acc[5] = fmaf(e, f2.y, acc[5]);
            acc[6] = fmaf(e, f3.x, acc[6]); acc[7] = fmaf(e, f3.y, acc[7]);
        }
    }
    // combine slots: u bit0 -> xor16, u bit1 -> xor32 (in-wave), u bit2 -> cross-wave LDS
#pragma unroll
    for (int o = 16; o <= 32; o <<= 1) {
        ls += __shfl_xor(ls, o);
#pragma unroll
        for (int i = 0; i < 8; ++i) acc[i] += __shfl_xor(acc[i], o);
    }
    __shared__ float sacc[16][9];
    __shared__ float sls;
    if (t >= 64 && t < 80) {
#pragma unroll
        for (int i = 0; i < 8; ++i) sacc[tx][i] = acc[i];
        if (t == 64) sls = ls;
    }
    __syncthreads();
    if (t < 16) {
        float inv = 1.f / (ls + sls + 1e-16f);
        float o8[8];
#pragma unroll
        for (int i = 0; i < 8; ++i) {
            float v = (acc[i] + sacc[tx][i]) * inv + bias[tx * 8 + i];
            o8[i] = (act && v < 0.f) ? 0.01f * v : v;
        }
        float4 w0 = {o8[0], o8[1], o8[2], o8[3]};
        float4 w1 = {o8[4], o8[5], o8[6], o8[7]};
        ((float4*)OUT)[(size_t)d * 32 + tx * 2]     = w0;
        ((float4*)OUT)[(size_t)d * 32 + tx * 2 + 1] = w1;
    }
}

extern "C" void kernel_launch(void* const* d_in, const int* in_sizes, int n_in,
                              void* d_out, int out_size, void* d_ws, size_t ws_size,
                              hipStream_t stream) {
    const float* x   = (const float*)d_in[0];
    const int*   ei  = (const int*)d_in[1];
    const float* W1  = (const float*)d_in[2];
    const float* as1 = (const float*)d_in[3];
    const float* ad1 = (const float*)d_in[4];
    const float* b1  = (const float*)d_in[5];
    const float* W2  = (const float*)d_in[6];
    const float* as2 = (const float*)d_in[7];
    const float* ad2 = (const float*)d_in[8];
    const float* b2  = (const float*)d_in[9];
    float* out = (float*)d_out;

    char* p = (char*)d_ws;
    auto alloc = [&](size_t bytes) { char* r = p; p += (bytes + 255) & ~size_t(255); return (void*)r; };
    int* bcnt  = (int*)alloc(sizeof(int) * NB);
    int* bbase = (int*)alloc(sizeof(int) * (NB + 1));
    int* bcur  = (int*)alloc(sizeof(int) * NB);
    int* off   = (int*)alloc(sizeof(int) * (N + 1));
    int* srcs  = (int*)alloc(sizeof(int) * ET);
    __half* H16 = (__half*)alloc(sizeof(__half) * (size_t)N * NF);
    float* AS  = (float*)alloc(sizeof(float) * N);
    float* AD  = (float*)alloc(sizeof(float) * N);
    float* HMID = (float*)alloc(sizeof(float) * (size_t)N * NF);
    int* packed = (int*)HMID;   // alias: packed is dead before HMID is first written

    // CSR build (bucketed two-level counting sort)
    k_zero_b<<<1, 512, 0, stream>>>(bcnt);
    k_hist<<<NBLK, 1024, 0, stream>>>(ei, bcnt);
    k_bscan<<<1, 512, 0, stream>>>(bcnt, bbase, bcur, off);
    k_binscatter<<<NBLK, 1024, 0, stream>>>(ei, bcur, packed);
    k_csr<<<NB, 1024, 0, stream>>>(packed, bbase, off, srcs);

    // layer 1
    k_gemm<<<N / GR, 256, 0, stream>>>(x, W1, as1, ad1, H16, AS, AD);
    k_aggregate<<<N, 128, 0, stream>>>(H16, AS, AD, off, srcs, b1, HMID, 1);
    // layer 2
    k_gemm<<<N / GR, 256, 0, stream>>>(HMID, W2, as2, ad2, H16, AS, AD);
    k_aggregate<<<N, 128, 0, stream>>>(H16, AS, AD, off, srcs, b2, out, 0);
}

// Round 5
// 286.395 us; speedup vs baseline: 2.9499x; 1.0568x over previous
//
#include <hip/hip_runtime.h>
#include <hip/hip_fp16.h>

constexpr int N  = 50000;
constexpr int E  = 1600000;
constexpr int ET = E + N;                   // with self-loops
constexpr int NF = 128;
constexpr int NB = (N + 127) / 128;         // 391 dst-buckets of 128 nodes
constexpr int EPB  = 8192;                  // edges per block (hist/scatter)
constexpr int NBLK = (ET + EPB - 1) / EPB;  // 202
constexpr int DCAP = 8192;                  // LDS edge capacity in k_csr
constexpr int GR = 16;                      // gemm rows per block
constexpr int SCAP = 512;                   // aggregate LDS edge stash capacity

__global__ __launch_bounds__(512) void k_zero_b(int* __restrict__ bcnt) {
    int i = threadIdx.x;
    if (i < NB) bcnt[i] = 0;
}

// per-block LDS histogram over 391 dst-buckets
__global__ __launch_bounds__(1024) void k_hist(const int* __restrict__ ei, int* __restrict__ bcnt) {
    __shared__ int h[NB];
    int t = threadIdx.x;
    for (int i = t; i < NB; i += 1024) h[i] = 0;
    __syncthreads();
    int base = blockIdx.x * EPB;
#pragma unroll
    for (int k = 0; k < EPB / 1024; ++k) {
        int i = base + k * 1024 + t;
        if (i < ET) {
            int d = (i < E) ? ei[E + i] : (i - E);
            atomicAdd(&h[d >> 7], 1);
        }
    }
    __syncthreads();
    for (int i = t; i < NB; i += 1024)
        if (h[i]) atomicAdd(&bcnt[i], h[i]);
}

// scan 391 bucket counts -> bbase (exclusive), bcur copy; set sentinels
__global__ __launch_bounds__(512) void k_bscan(const int* __restrict__ bcnt,
                                               int* __restrict__ bbase, int* __restrict__ bcur,
                                               int* __restrict__ off) {
    __shared__ int buf[512];
    int t = threadIdx.x;
    int v = (t < NB) ? bcnt[t] : 0;
    buf[t] = v;
    __syncthreads();
    for (int o = 1; o < 512; o <<= 1) {
        int a = (t >= o) ? buf[t - o] : 0;
        __syncthreads();
        buf[t] += a;
        __syncthreads();
    }
    if (t < NB) { bbase[t] = buf[t] - v; bcur[t] = buf[t] - v; }
    if (t == 0) { bbase[NB] = ET; off[N] = ET; }
}

// bucket-binned scatter: stash 8 edges in registers, LDS-count, reserve one
// contiguous global run per (block,bucket), append packed (src | dlow<<16)
__global__ __launch_bounds__(1024) void k_binscatter(const int* __restrict__ ei,
                                                     int* __restrict__ bcur,
                                                     int* __restrict__ packed) {
    __shared__ int h[NB], lcur[NB], garr[NB];
    int t = threadIdx.x;
    for (int i = t; i < NB; i += 1024) h[i] = 0;
    __syncthreads();
    int base = blockIdx.x * EPB;
    int pk[EPB / 1024];
    int bk[EPB / 1024];
#pragma unroll
    for (int k = 0; k < EPB / 1024; ++k) {
        int i = base + k * 1024 + t;
        if (i < ET) {
            int s, d;
            if (i < E) { s = ei[i]; d = ei[E + i]; } else { s = i - E; d = i - E; }
            bk[k] = d >> 7;
            pk[k] = s | ((d & 127) << 16);
            atomicAdd(&h[bk[k]], 1);
        } else bk[k] = -1;
    }
    __syncthreads();
    for (int i = t; i < NB; i += 1024) {
        lcur[i] = 0;
        garr[i] = h[i] ? atomicAdd(&bcur[i], h[i]) : 0;
    }
    __syncthreads();
#pragma unroll
    for (int k = 0; k < EPB / 1024; ++k) {
        if (bk[k] >= 0) {
            int p = garr[bk[k]] + atomicAdd(&lcur[bk[k]], 1);
            packed[p] = pk[k];
        }
    }
}

// one block per bucket: local CSR over its 128 dsts in LDS; srcs stored as uint16
__global__ __launch_bounds__(1024) void k_csr(const int* __restrict__ packed,
                                              const int* __restrict__ bbase,
                                              int* __restrict__ off,
                                              unsigned short* __restrict__ srcs) {
    int b = blockIdx.x;
    int t = threadIdx.x;
    int s0 = bbase[b], s1 = bbase[b + 1];
    int n = s1 - s0;
    __shared__ int buf[DCAP];
    __shared__ int h[128], sc[128], lcur[128];
    for (int i = t; i < n && i < DCAP; i += 1024) buf[i] = packed[s0 + i];
    if (t < 128) { h[t] = 0; lcur[t] = 0; }
    __syncthreads();
    for (int i = t; i < n; i += 1024) {
        int p = (i < DCAP) ? buf[i] : packed[s0 + i];
        atomicAdd(&h[(p >> 16) & 127], 1);
    }
    __syncthreads();
    if (t < 128) sc[t] = h[t];
    __syncthreads();
    for (int o = 1; o < 128; o <<= 1) {
        int a = (t >= o && t < 128) ? sc[t - o] : 0;
        __syncthreads();
        if (t < 128) sc[t] += a;
        __syncthreads();
    }
    if (t < 128) {
        int d = b * 128 + t;
        if (d < N) off[d] = s0 + sc[t] - h[t];
    }
    __syncthreads();
    for (int i = t; i < n; i += 1024) {
        int p = (i < DCAP) ? buf[i] : packed[s0 + i];
        int dl = (p >> 16) & 127;
        int pos = s0 + (sc[dl] - h[dl]) + atomicAdd(&lcur[dl], 1);
        srcs[pos] = (unsigned short)(p & 0xFFFF);
    }
}

// H16 = fp16(X @ W), alpha projections fused from fp32 accumulators
__global__ __launch_bounds__(256) void k_gemm(
    const float* __restrict__ X, const float* __restrict__ W,
    const float* __restrict__ asv, const float* __restrict__ adv,
    __half* __restrict__ H16, float* __restrict__ AS, float* __restrict__ AD) {
    int brow = blockIdx.x * GR;
    int t = threadIdx.x;
    int c = t & 127, ty = t >> 7;
    __shared__ float4 xs[GR][NF / 4];
    for (int idx = t; idx < GR * (NF / 4); idx += 256) {
        int r = idx >> 5, q = idx & 31;
        xs[r][q] = ((const float4*)X)[(size_t)(brow + r) * (NF / 4) + q];
    }
    __syncthreads();
    float acc[8] = {0.f, 0.f, 0.f, 0.f, 0.f, 0.f, 0.f, 0.f};
#pragma unroll 4
    for (int k4 = 0; k4 < NF / 4; ++k4) {
        float w0 = W[(k4 * 4 + 0) * NF + c];
        float w1 = W[(k4 * 4 + 1) * NF + c];
        float w2 = W[(k4 * 4 + 2) * NF + c];
        float w3 = W[(k4 * 4 + 3) * NF + c];
#pragma unroll
        for (int rr = 0; rr < 8; ++rr) {
            float4 x4 = xs[ty * 8 + rr][k4];
            acc[rr] = fmaf(x4.x, w0, fmaf(x4.y, w1, fmaf(x4.z, w2, fmaf(x4.w, w3, acc[rr]))));
        }
    }
    float avs = asv[c], avd = adv[c];
    __shared__ float rsum[GR][2][2];   // [row][as/ad][wave-half]
#pragma unroll
    for (int rr = 0; rr < 8; ++rr) {
        H16[(size_t)(brow + ty * 8 + rr) * NF + c] = __float2half_rn(acc[rr]);
        float ps = acc[rr] * avs;
        float pd = acc[rr] * avd;
#pragma unroll
        for (int o = 32; o > 0; o >>= 1) { ps += __shfl_down(ps, o); pd += __shfl_down(pd, o); }
        if ((t & 63) == 0) {
            int half = (t >> 6) & 1;
            rsum[ty * 8 + rr][0][half] = ps;
            rsum[ty * 8 + rr][1][half] = pd;
        }
    }
    __syncthreads();
    if (t < GR) {
        AS[brow + t] = rsum[t][0][0] + rsum[t][0][1];
        AD[brow + t] = rsum[t][1][0] + rsum[t][1][1];
    }
}

// per-destination softmax + aggregate, LDS edge stash:
//   phase A: stash post-leaky logits+srcs, block max
//   phase B: ONE exp per edge -> stashed weight + denominator
//   phase C: 8 edge slots x 16 lanes gather H16 rows, weights broadcast from LDS
__global__ __launch_bounds__(128) void k_aggregate(
    const __half* __restrict__ H16, const float* __restrict__ AS, const float* __restrict__ AD,
    const int* __restrict__ off, const unsigned short* __restrict__ srcs,
    const float* __restrict__ bias, float* __restrict__ OUT, int act) {
    int d = blockIdx.x;
    int t = threadIdx.x;
    int tx = t & 15, u = t >> 4;              // u: edge slot 0..7
    int beg = off[d], end = off[d + 1];
    int deg = end - beg;
    float ad = AD[d];

    __shared__ float ssv[SCAP];
    __shared__ int   ssrc[SCAP];
    __shared__ float red[2];

    // phase A: load, leaky, stash, block max
    float lm = -3.0e38f;
    for (int i = t; i < deg; i += 128) {
        int s = srcs[beg + i];
        float sv = AS[s] + ad;
        sv = (sv > 0.f) ? sv : 0.2f * sv;
        if (i < SCAP) { ssv[i] = sv; ssrc[i] = s; }
        lm = fmaxf(lm, sv);
    }
#pragma unroll
    for (int o = 32; o > 0; o >>= 1) lm = fmaxf(lm, __shfl_xor(lm, o));
    if ((t & 63) == 0) red[t >> 6] = lm;
    __syncthreads();
    float m = fmaxf(red[0], red[1]);

    // phase B: one exp per edge, accumulate denominator
    float ls = 0.f;
    int dcap = (deg < SCAP) ? deg : SCAP;
    for (int i = t; i < dcap; i += 128) {
        float e = __expf(ssv[i] - m);
        ssv[i] = e;
        ls += e;
    }
    for (int i = SCAP + t; i < deg; i += 128) {   // overflow (cold path)
        int s = srcs[beg + i];
        float sv = AS[s] + ad;
        sv = (sv > 0.f) ? sv : 0.2f * sv;
        ls += __expf(sv - m);
    }
#pragma unroll
    for (int o = 32; o > 0; o >>= 1) ls += __shfl_xor(ls, o);
    __syncthreads();                 // ssv rewrites done before reuse of red
    if ((t & 63) == 0) red[t >> 6] = ls;
    __syncthreads();
    float inv = 1.f / (red[0] + red[1] + 1e-16f);

    // phase C: gather-accumulate, 8 edges in flight
    float acc[8] = {0.f, 0.f, 0.f, 0.f, 0.f, 0.f, 0.f, 0.f};
    for (int j0 = 0; j0 < deg; j0 += 8) {
        int i = j0 + u;
        if (i < deg) {
            float e;
            int s;
            if (i < SCAP) { e = ssv[i]; s = ssrc[i]; }
            else {                                     // overflow (cold path)
                s = srcs[beg + i];
                float sv = AS[s] + ad;
                sv = (sv > 0.f) ? sv : 0.2f * sv;
                e = __expf(sv - m);
            }
            union { float4 f; __half2 h[4]; } v;
            v.f = *reinterpret_cast<const float4*>(H16 + (size_t)s * NF + tx * 8);
            float2 f0 = __half22float2(v.h[0]);
            float2 f1 = __half22float2(v.h[1]);
            float2 f2 = __half22float2(v.h[2]);
            float2 f3 = __half22float2(v.h[3]);
            acc[0] = fmaf(e, f0.x, acc[0]); acc[1] = fmaf(e, f0.y, acc[1]);
            acc[2] = fmaf(e, f1.x, acc[2]); acc[3] = fmaf(e, f1.y, acc[3]);
            acc[4] = fmaf(e, f2.x, acc[4]); acc[5] = fmaf(e, f2.y, acc[5]);
            acc[6] = fmaf(e, f3.x, acc[6]); acc[7] = fmaf(e, f3.y, acc[7]);
        }
    }
    // combine slots: xor16 + xor32 in-wave, then cross-wave via LDS
#pragma unroll
    for (int o = 16; o <= 32; o <<= 1) {
#pragma unroll
        for (int i = 0; i < 8; ++i) acc[i] += __shfl_xor(acc[i], o);
    }
    __shared__ float sacc[16][9];
    if (t >= 64 && t < 80) {
#pragma unroll
        for (int i = 0; i < 8; ++i) sacc[tx][i] = acc[i];
    }
    __syncthreads();
    if (t < 16) {
        float o8[8];
#pragma unroll
        for (int i = 0; i < 8; ++i) {
            float v = (acc[i] + sacc[tx][i]) * inv + bias[tx * 8 + i];
            o8[i] = (act && v < 0.f) ? 0.01f * v : v;
        }
        float4 w0 = {o8[0], o8[1], o8[2], o8[3]};
        float4 w1 = {o8[4], o8[5], o8[6], o8[7]};
        ((float4*)OUT)[(size_t)d * 32 + tx * 2]     = w0;
        ((float4*)OUT)[(size_t)d * 32 + tx * 2 + 1] = w1;
    }
}

extern "C" void kernel_launch(void* const* d_in, const int* in_sizes, int n_in,
                              void* d_out, int out_size, void* d_ws, size_t ws_size,
                              hipStream_t stream) {
    const float* x   = (const float*)d_in[0];
    const int*   ei  = (const int*)d_in[1];
    const float* W1  = (const float*)d_in[2];
    const float* as1 = (const float*)d_in[3];
    const float* ad1 = (const float*)d_in[4];
    const float* b1  = (const float*)d_in[5];
    const float* W2  = (const float*)d_in[6];
    const float* as2 = (const float*)d_in[7];
    const float* ad2 = (const float*)d_in[8];
    const float* b2  = (const float*)d_in[9];
    float* out = (float*)d_out;

    char* p = (char*)d_ws;
    auto alloc = [&](size_t bytes) { char* r = p; p += (bytes + 255) & ~size_t(255); return (void*)r; };
    int* bcnt  = (int*)alloc(sizeof(int) * NB);
    int* bbase = (int*)alloc(sizeof(int) * (NB + 1));
    int* bcur  = (int*)alloc(sizeof(int) * NB);
    int* off   = (int*)alloc(sizeof(int) * (N + 1));
    unsigned short* srcs = (unsigned short*)alloc(sizeof(unsigned short) * ET);
    __half* H16 = (__half*)alloc(sizeof(__half) * (size_t)N * NF);
    float* AS  = (float*)alloc(sizeof(float) * N);
    float* AD  = (float*)alloc(sizeof(float) * N);
    float* HMID = (float*)alloc(sizeof(float) * (size_t)N * NF);
    int* packed = (int*)HMID;   // alias: packed is dead before HMID is first written

    // CSR build (bucketed two-level counting sort)
    k_zero_b<<<1, 512, 0, stream>>>(bcnt);
    k_hist<<<NBLK, 1024, 0, stream>>>(ei, bcnt);
    k_bscan<<<1, 512, 0, stream>>>(bcnt, bbase, bcur, off);
    k_binscatter<<<NBLK, 1024, 0, stream>>>(ei, bcur, packed);
    k_csr<<<NB, 1024, 0, stream>>>(packed, bbase, off, srcs);

    // layer 1
    k_gemm<<<N / GR, 256, 0, stream>>>(x, W1, as1, ad1, H16, AS, AD);
    k_aggregate<<<N, 128, 0, stream>>>(H16, AS, AD, off, srcs, b1, HMID, 1);
    // layer 2
    k_gemm<<<N / GR, 256, 0, stream>>>(HMID, W2, as2, ad2, H16, AS, AD);
    k_aggregate<<<N, 128, 0, stream>>>(H16, AS, AD, off, srcs, b2, out, 0);
}

// Round 6
// 217.589 us; speedup vs baseline: 3.8827x; 1.3162x over previous
//
#include <hip/hip_runtime.h>
#include <hip/hip_fp16.h>

constexpr int N  = 50000;
constexpr int E  = 1600000;
constexpr int ET = E + N;                   // with self-loops
constexpr int NF = 128;
constexpr int NB = (N + 127) / 128;         // 391 dst-buckets of 128 nodes
constexpr int EPB  = 8192;                  // edges per block (hist/scatter)
constexpr int NBLK = (ET + EPB - 1) / EPB;  // 202
constexpr int DCAP = 8192;                  // LDS edge capacity in k_csr
constexpr int SCAP = 512;                   // aggregate LDS edge stash capacity

typedef _Float16 half8 __attribute__((ext_vector_type(8)));
typedef float    f32x4 __attribute__((ext_vector_type(4)));

__global__ __launch_bounds__(512) void k_zero_b(int* __restrict__ bcnt) {
    int i = threadIdx.x;
    if (i < NB) bcnt[i] = 0;
}

__global__ __launch_bounds__(1024) void k_hist(const int* __restrict__ ei, int* __restrict__ bcnt) {
    __shared__ int h[NB];
    int t = threadIdx.x;
    for (int i = t; i < NB; i += 1024) h[i] = 0;
    __syncthreads();
    int base = blockIdx.x * EPB;
#pragma unroll
    for (int k = 0; k < EPB / 1024; ++k) {
        int i = base + k * 1024 + t;
        if (i < ET) {
            int d = (i < E) ? ei[E + i] : (i - E);
            atomicAdd(&h[d >> 7], 1);
        }
    }
    __syncthreads();
    for (int i = t; i < NB; i += 1024)
        if (h[i]) atomicAdd(&bcnt[i], h[i]);
}

__global__ __launch_bounds__(512) void k_bscan(const int* __restrict__ bcnt,
                                               int* __restrict__ bbase, int* __restrict__ bcur,
                                               int* __restrict__ off) {
    __shared__ int buf[512];
    int t = threadIdx.x;
    int v = (t < NB) ? bcnt[t] : 0;
    buf[t] = v;
    __syncthreads();
    for (int o = 1; o < 512; o <<= 1) {
        int a = (t >= o) ? buf[t - o] : 0;
        __syncthreads();
        buf[t] += a;
        __syncthreads();
    }
    if (t < NB) { bbase[t] = buf[t] - v; bcur[t] = buf[t] - v; }
    if (t == 0) { bbase[NB] = ET; off[N] = ET; }
}

__global__ __launch_bounds__(1024) void k_binscatter(const int* __restrict__ ei,
                                                     int* __restrict__ bcur,
                                                     int* __restrict__ packed) {
    __shared__ int h[NB], lcur[NB], garr[NB];
    int t = threadIdx.x;
    for (int i = t; i < NB; i += 1024) h[i] = 0;
    __syncthreads();
    int base = blockIdx.x * EPB;
    int pk[EPB / 1024];
    int bk[EPB / 1024];
#pragma unroll
    for (int k = 0; k < EPB / 1024; ++k) {
        int i = base + k * 1024 + t;
        if (i < ET) {
            int s, d;
            if (i < E) { s = ei[i]; d = ei[E + i]; } else { s = i - E; d = i - E; }
            bk[k] = d >> 7;
            pk[k] = s | ((d & 127) << 16);
            atomicAdd(&h[bk[k]], 1);
        } else bk[k] = -1;
    }
    __syncthreads();
    for (int i = t; i < NB; i += 1024) {
        lcur[i] = 0;
        garr[i] = h[i] ? atomicAdd(&bcur[i], h[i]) : 0;
    }
    __syncthreads();
#pragma unroll
    for (int k = 0; k < EPB / 1024; ++k) {
        if (bk[k] >= 0) {
            int p = garr[bk[k]] + atomicAdd(&lcur[bk[k]], 1);
            packed[p] = pk[k];
        }
    }
}

__global__ __launch_bounds__(1024) void k_csr(const int* __restrict__ packed,
                                              const int* __restrict__ bbase,
                                              int* __restrict__ off,
                                              unsigned short* __restrict__ srcs) {
    int b = blockIdx.x;
    int t = threadIdx.x;
    int s0 = bbase[b], s1 = bbase[b + 1];
    int n = s1 - s0;
    __shared__ int buf[DCAP];
    __shared__ int h[128], sc[128], lcur[128];
    for (int i = t; i < n && i < DCAP; i += 1024) buf[i] = packed[s0 + i];
    if (t < 128) { h[t] = 0; lcur[t] = 0; }
    __syncthreads();
    for (int i = t; i < n; i += 1024) {
        int p = (i < DCAP) ? buf[i] : packed[s0 + i];
        atomicAdd(&h[(p >> 16) & 127], 1);
    }
    __syncthreads();
    if (t < 128) sc[t] = h[t];
    __syncthreads();
    for (int o = 1; o < 128; o <<= 1) {
        int a = (t >= o && t < 128) ? sc[t - o] : 0;
        __syncthreads();
        if (t < 128) sc[t] += a;
        __syncthreads();
    }
    if (t < 128) {
        int d = b * 128 + t;
        if (d < N) off[d] = s0 + sc[t] - h[t];
    }
    __syncthreads();
    for (int i = t; i < n; i += 1024) {
        int p = (i < DCAP) ? buf[i] : packed[s0 + i];
        int dl = (p >> 16) & 127;
        int pos = s0 + (sc[dl] - h[dl]) + atomicAdd(&lcur[dl], 1);
        srcs[pos] = (unsigned short)(p & 0xFFFF);
    }
}

// x (fp32) -> fp16, 4 elems/thread
__global__ __launch_bounds__(256) void k_cvt_x(const float* __restrict__ X, __half* __restrict__ X16) {
    int i = blockIdx.x * 256 + threadIdx.x;           // i indexes float4
    if (i >= N * NF / 4) return;
    float4 v = ((const float4*)X)[i];
    union { __half2 h[2]; uint2 u; } pk;
    pk.h[0] = __floats2half2_rn(v.x, v.y);
    pk.h[1] = __floats2half2_rn(v.z, v.w);
    ((uint2*)X16)[i] = pk.u;
}

// pack W1,W2 (fp32 [k][n]) into MFMA B-fragment order, fp16:
// Wpk[((ks*8+ct)*64+lane)*8+j] = W[(ks*32+(lane>>4)*8+j)][ct*16+(lane&15)]
__global__ __launch_bounds__(256) void k_packw(const float* __restrict__ W1, const float* __restrict__ W2,
                                               __half* __restrict__ P1, __half* __restrict__ P2) {
    int tid = blockIdx.x * 256 + threadIdx.x;
    if (tid >= 2 * NF * NF) return;
    int which = tid >> 14;
    int id = tid & (NF * NF - 1);
    int k = id >> 7, n = id & 127;
    const float* W = which ? W2 : W1;
    __half* P = which ? P2 : P1;
    int ks = k >> 5, r = k & 31, ct = n >> 4;
    int lane = ((r >> 3) << 4) | (n & 15);
    int j = r & 7;
    P[((ks * 8 + ct) * 64 + lane) * 8 + j] = __float2half_rn(W[k * NF + n]);
}

// H16 = fp16(A16 @ W) via mfma_f32_16x16x32_f16; alpha projections fused.
// 64 rows/block, 4 waves; wave w: rows blk*64+w*16 .. +15, cols 0..127.
__global__ __launch_bounds__(256) void k_gemm_mfma(
    const __half* __restrict__ A16, const __half* __restrict__ Wpk,
    const float* __restrict__ asv, const float* __restrict__ adv,
    __half* __restrict__ H16, float* __restrict__ AS, float* __restrict__ AD) {
    int t = threadIdx.x;
    int wave = t >> 6, lane = t & 63;
    int base = blockIdx.x * 64 + wave * 16;

    int row_a = base + (lane & 15);
    if (row_a >= N) row_a = N - 1;                     // clamp loads; stores guarded
    const half8* Arow = (const half8*)(A16 + (size_t)row_a * NF);
    const half8* BP = (const half8*)Wpk;

    f32x4 acc[8] = {};
#pragma unroll
    for (int ks = 0; ks < 4; ++ks) {
        half8 a = Arow[ks * 4 + (lane >> 4)];
#pragma unroll
        for (int ct = 0; ct < 8; ++ct) {
            half8 b = BP[(ks * 8 + ct) * 64 + lane];
            acc[ct] = __builtin_amdgcn_mfma_f32_16x16x32_f16(a, b, acc[ct], 0, 0, 0);
        }
    }

    // epilogue: C/D layout col=lane&15, row=base+(lane>>4)*4+r
    int colb = lane & 15;
    int rowq = base + (lane >> 4) * 4;
    float ps[4] = {0.f, 0.f, 0.f, 0.f};
    float pd[4] = {0.f, 0.f, 0.f, 0.f};
#pragma unroll
    for (int ct = 0; ct < 8; ++ct) {
        int col = ct * 16 + colb;
        float av = asv[col], dv = adv[col];
#pragma unroll
        for (int r = 0; r < 4; ++r) {
            float h = acc[ct][r];
            if (rowq + r < N) H16[(size_t)(rowq + r) * NF + col] = __float2half_rn(h);
            ps[r] = fmaf(h, av, ps[r]);
            pd[r] = fmaf(h, dv, pd[r]);
        }
    }
#pragma unroll
    for (int r = 0; r < 4; ++r) {
#pragma unroll
        for (int o = 1; o <= 8; o <<= 1) {
            ps[r] += __shfl_xor(ps[r], o);
            pd[r] += __shfl_xor(pd[r], o);
        }
    }
    if (colb == 0) {
#pragma unroll
        for (int r = 0; r < 4; ++r) {
            if (rowq + r < N) { AS[rowq + r] = ps[r]; AD[rowq + r] = pd[r]; }
        }
    }
}

// per-destination softmax + aggregate (LDS edge stash, one exp per edge)
template <typename OUTT, int ACT>
__global__ __launch_bounds__(128) void k_aggregate(
    const __half* __restrict__ H16, const float* __restrict__ AS, const float* __restrict__ AD,
    const int* __restrict__ off, const unsigned short* __restrict__ srcs,
    const float* __restrict__ bias, OUTT* __restrict__ OUT) {
    int d = blockIdx.x;
    int t = threadIdx.x;
    int tx = t & 15, u = t >> 4;              // u: edge slot 0..7
    int beg = off[d], end = off[d + 1];
    int deg = end - beg;
    float ad = AD[d];

    __shared__ float ssv[SCAP];
    __shared__ int   ssrc[SCAP];
    __shared__ float red[2];

    // phase A: load, leaky, stash, block max
    float lm = -3.0e38f;
    for (int i = t; i < deg; i += 128) {
        int s = srcs[beg + i];
        float sv = AS[s] + ad;
        sv = (sv > 0.f) ? sv : 0.2f * sv;
        if (i < SCAP) { ssv[i] = sv; ssrc[i] = s; }
        lm = fmaxf(lm, sv);
    }
#pragma unroll
    for (int o = 32; o > 0; o >>= 1) lm = fmaxf(lm, __shfl_xor(lm, o));
    if ((t & 63) == 0) red[t >> 6] = lm;
    __syncthreads();
    float m = fmaxf(red[0], red[1]);

    // phase B: one exp per edge, denominator
    float ls = 0.f;
    int dcap = (deg < SCAP) ? deg : SCAP;
    for (int i = t; i < dcap; i += 128) {
        float e = __expf(ssv[i] - m);
        ssv[i] = e;
        ls += e;
    }
    for (int i = SCAP + t; i < deg; i += 128) {   // overflow (cold path)
        int s = srcs[beg + i];
        float sv = AS[s] + ad;
        sv = (sv > 0.f) ? sv : 0.2f * sv;
        ls += __expf(sv - m);
    }
#pragma unroll
    for (int o = 32; o > 0; o >>= 1) ls += __shfl_xor(ls, o);
    __syncthreads();
    if ((t & 63) == 0) red[t >> 6] = ls;
    __syncthreads();
    float inv = 1.f / (red[0] + red[1] + 1e-16f);

    // phase C: gather-accumulate, 8 edges in flight
    float acc[8] = {0.f, 0.f, 0.f, 0.f, 0.f, 0.f, 0.f, 0.f};
    for (int j0 = 0; j0 < deg; j0 += 8) {
        int i = j0 + u;
        if (i < deg) {
            float e;
            int s;
            if (i < SCAP) { e = ssv[i]; s = ssrc[i]; }
            else {
                s = srcs[beg + i];
                float sv = AS[s] + ad;
                sv = (sv > 0.f) ? sv : 0.2f * sv;
                e = __expf(sv - m);
            }
            union { float4 f; __half2 h[4]; } v;
            v.f = *reinterpret_cast<const float4*>(H16 + (size_t)s * NF + tx * 8);
            float2 f0 = __half22float2(v.h[0]);
            float2 f1 = __half22float2(v.h[1]);
            float2 f2 = __half22float2(v.h[2]);
            float2 f3 = __half22float2(v.h[3]);
            acc[0] = fmaf(e, f0.x, acc[0]); acc[1] = fmaf(e, f0.y, acc[1]);
            acc[2] = fmaf(e, f1.x, acc[2]); acc[3] = fmaf(e, f1.y, acc[3]);
            acc[4] = fmaf(e, f2.x, acc[4]); acc[5] = fmaf(e, f2.y, acc[5]);
            acc[6] = fmaf(e, f3.x, acc[6]); acc[7] = fmaf(e, f3.y, acc[7]);
        }
    }
#pragma unroll
    for (int o = 16; o <= 32; o <<= 1) {
#pragma unroll
        for (int i = 0; i < 8; ++i) acc[i] += __shfl_xor(acc[i], o);
    }
    __shared__ float sacc[16][9];
    if (t >= 64 && t < 80) {
#pragma unroll
        for (int i = 0; i < 8; ++i) sacc[tx][i] = acc[i];
    }
    __syncthreads();
    if (t < 16) {
        float o8[8];
#pragma unroll
        for (int i = 0; i < 8; ++i) {
            float v = (acc[i] + sacc[tx][i]) * inv + bias[tx * 8 + i];
            o8[i] = (ACT && v < 0.f) ? 0.01f * v : v;
        }
        if constexpr (sizeof(OUTT) == 2) {
            union { __half2 h[4]; float4 f; } pk;
            pk.h[0] = __floats2half2_rn(o8[0], o8[1]);
            pk.h[1] = __floats2half2_rn(o8[2], o8[3]);
            pk.h[2] = __floats2half2_rn(o8[4], o8[5]);
            pk.h[3] = __floats2half2_rn(o8[6], o8[7]);
            ((float4*)OUT)[(size_t)d * 16 + tx] = pk.f;
        } else {
            float4 w0 = {o8[0], o8[1], o8[2], o8[3]};
            float4 w1 = {o8[4], o8[5], o8[6], o8[7]};
            ((float4*)OUT)[(size_t)d * 32 + tx * 2]     = w0;
            ((float4*)OUT)[(size_t)d * 32 + tx * 2 + 1] = w1;
        }
    }
}

extern "C" void kernel_launch(void* const* d_in, const int* in_sizes, int n_in,
                              void* d_out, int out_size, void* d_ws, size_t ws_size,
                              hipStream_t stream) {
    const float* x   = (const float*)d_in[0];
    const int*   ei  = (const int*)d_in[1];
    const float* W1  = (const float*)d_in[2];
    const float* as1 = (const float*)d_in[3];
    const float* ad1 = (const float*)d_in[4];
    const float* b1  = (const float*)d_in[5];
    const float* W2  = (const float*)d_in[6];
    const float* as2 = (const float*)d_in[7];
    const float* ad2 = (const float*)d_in[8];
    const float* b2  = (const float*)d_in[9];
    float* out = (float*)d_out;

    char* p = (char*)d_ws;
    auto alloc = [&](size_t bytes) { char* r = p; p += (bytes + 255) & ~size_t(255); return (void*)r; };
    int* bcnt  = (int*)alloc(sizeof(int) * NB);
    int* bbase = (int*)alloc(sizeof(int) * (NB + 1));
    int* bcur  = (int*)alloc(sizeof(int) * NB);
    int* off   = (int*)alloc(sizeof(int) * (N + 1));
    unsigned short* srcs = (unsigned short*)alloc(sizeof(unsigned short) * ET);
    __half* X16   = (__half*)alloc(sizeof(__half) * (size_t)N * NF);
    __half* H16   = (__half*)alloc(sizeof(__half) * (size_t)N * NF);
    __half* HMID16= (__half*)alloc(sizeof(__half) * (size_t)N * NF);
    __half* Wpk1  = (__half*)alloc(sizeof(__half) * NF * NF);
    __half* Wpk2  = (__half*)alloc(sizeof(__half) * NF * NF);
    float* AS  = (float*)alloc(sizeof(float) * N);
    float* AD  = (float*)alloc(sizeof(float) * N);
    int* packed = (int*)alloc(sizeof(int) * ET);

    // CSR build (bucketed two-level counting sort)
    k_zero_b<<<1, 512, 0, stream>>>(bcnt);
    k_hist<<<NBLK, 1024, 0, stream>>>(ei, bcnt);
    k_bscan<<<1, 512, 0, stream>>>(bcnt, bbase, bcur, off);
    k_binscatter<<<NBLK, 1024, 0, stream>>>(ei, bcur, packed);
    k_csr<<<NB, 1024, 0, stream>>>(packed, bbase, off, srcs);

    // fp16 conversions / weight packing
    k_cvt_x<<<(N * NF / 4 + 255) / 256, 256, 0, stream>>>(x, X16);
    k_packw<<<(2 * NF * NF + 255) / 256, 256, 0, stream>>>(W1, W2, Wpk1, Wpk2);

    // layer 1
    k_gemm_mfma<<<(N + 63) / 64, 256, 0, stream>>>(X16, Wpk1, as1, ad1, H16, AS, AD);
    k_aggregate<__half, 1><<<N, 128, 0, stream>>>(H16, AS, AD, off, srcs, b1, HMID16);
    // layer 2
    k_gemm_mfma<<<(N + 63) / 64, 256, 0, stream>>>(HMID16, Wpk2, as2, ad2, H16, AS, AD);
    k_aggregate<float, 0><<<N, 128, 0, stream>>>(H16, AS, AD, off, srcs, b2, out);
}